// Round 14
// baseline (91.420 us; speedup 1.0000x reference)
//
#include <hip/hip_runtime.h>

#define BATCH 2
#define CDIM 256
#define NPIX 2304      // 48*48
#define NHEAD 8
#define DH 64
#define HID 512
#define NMEM 4
#define NKV 2308       // NMEM + NPIX
#define NKVP 2368      // NKV padded to multiple of 64 (zeroed pad)
#define QSCALE 0.125f  // 64^-0.5
#define LOG2E 1.4426950408889634f
#define WQKV_E 393216  // 1536*256
#define WOUT_E 131072  // 256*512
#define KVSPLIT 1216   // half 0: kv 0..1215 (19 tiles); half 1: 1216..2367 (18)

typedef float f32x4 __attribute__((ext_vector_type(4)));
typedef __bf16 bf16x8 __attribute__((ext_vector_type(8)));
typedef unsigned short u16;
typedef u16 u16x4 __attribute__((ext_vector_type(4)));
typedef u16 u16x8 __attribute__((ext_vector_type(8)));
typedef unsigned u32x2 __attribute__((ext_vector_type(2)));

#if __has_builtin(__builtin_amdgcn_exp2f)
#define EXP2(x) __builtin_amdgcn_exp2f(x)
#else
#define EXP2(x) exp2f(x)
#endif

static __device__ __forceinline__ u16 f2b(float f) {
  union { float f; unsigned u; } a; a.f = f;
  unsigned u = a.u;
  u += 0x7fffu + ((u >> 16) & 1u);   // RNE
  return (u16)(u >> 16);
}
static __device__ __forceinline__ float b2f(u16 b) {
  union { float f; unsigned u; } a; a.u = ((unsigned)b) << 16; return a.f;
}

// ---------------- Kernel 1: merged prep + RMSNorm ------------------------------
// blocks 0..255: wb = bf16(wqkv * (1+gamma) [* QSCALE*LOG2E on q rows]) | bf16(wout)
// blocks 256..271: mem kv tokens; 272..335: zero vT pad; 336..623: RMSNorm->xnT
__global__ __launch_bounds__(256) void k_prep(
    const float* __restrict__ wqkv, const float* __restrict__ wout,
    const float* __restrict__ gamma, const float* __restrict__ mem_kv,
    const float* __restrict__ x,
    u16* __restrict__ wb, u16* __restrict__ kk, u16* __restrict__ vT,
    u16* __restrict__ xnT)
{
  __shared__ float xs[16 * 261];
  __shared__ float red[16][17];
  __shared__ float rsh[16];
  const int blk = blockIdx.x, t = threadIdx.x;
  if (blk < 256) {
    const int i0 = (blk * 256 + t) * 8;
    u16x8 o;
    if (i0 < WQKV_E) {
      const float sc = ((i0 >> 8) < 512) ? QSCALE * LOG2E : 1.0f;
      const int c0 = i0 & 255;
      const f32x4 a = *(const f32x4*)&wqkv[i0];
      const f32x4 b = *(const f32x4*)&wqkv[i0 + 4];
      const f32x4 g0 = *(const f32x4*)&gamma[c0];
      const f32x4 g1 = *(const f32x4*)&gamma[c0 + 4];
#pragma unroll
      for (int e = 0; e < 4; ++e) {
        o[e]     = f2b(a[e] * sc * (1.0f + g0[e]));
        o[e + 4] = f2b(b[e] * sc * (1.0f + g1[e]));
      }
    } else {
      const f32x4 a = *(const f32x4*)&wout[i0 - WQKV_E];
      const f32x4 b = *(const f32x4*)&wout[i0 - WQKV_E + 4];
#pragma unroll
      for (int e = 0; e < 4; ++e) { o[e] = f2b(a[e]); o[e + 4] = f2b(b[e]); }
    }
    *(u16x8*)&wb[i0] = o;
  } else if (blk < 272) {
    const int idx = (blk - 256) * 256 + t;   // 0..4095 = b,h,m,d
    const int d = idx & 63;
    const int m = (idx >> 6) & 3;
    const int h = (idx >> 8) & 7;
    const int b = idx >> 11;
    const float mk = mem_kv[((size_t)h * NMEM + m) * DH + d];
    const float mv = mem_kv[(((size_t)NHEAD + h) * NMEM + m) * DH + d];
    kk[(((size_t)(b * NHEAD + h)) * NKV + m) * DH + d] = f2b(mk);
    vT[(((size_t)(b * NHEAD + h)) * DH + d) * NKVP + m] = f2b(mv);
  } else if (blk < 336) {
    const int gid = (blk - 272) * 256 + t;   // 0..16383
    const int row = gid >> 4;                 // bh*64+d
    const int c0 = (gid & 15) * 4 + 2304;
    u16x4 z = {0, 0, 0, 0};
    *(u16x4*)&vT[(size_t)row * NKVP + c0] = z;
  } else {
    // RMSNorm -> xn^T bf16 [b*p][c] (gamma folded into weights)
    const int blk2 = blk - 336;
    const int b = blk2 / 144;
    const int p0 = (blk2 % 144) * 16;
    const int px = t & 15, cg = t >> 4;
    const float* xb = x + (size_t)b * CDIM * NPIX + p0 + px;
    float ssq = 0.f;
#pragma unroll
    for (int i = 0; i < 16; ++i) {
      const int c = cg * 16 + i;
      const float v = xb[(size_t)c * NPIX];
      xs[px * 261 + c] = v;
      ssq += v * v;
    }
    red[px][cg] = ssq;
    __syncthreads();
    if (t < 16) {
      float s = 0.f;
#pragma unroll
      for (int i = 0; i < 16; ++i) s += red[t][i];
      rsh[t] = 16.0f / fmaxf(sqrtf(s), 1e-12f);   // sqrt(CDIM)=16
    }
    __syncthreads();
    {
      const int pp = t >> 4, c0 = (t & 15) * 16;
      const float rs = rsh[pp];
      u16x8 o0, o1;
#pragma unroll
      for (int e = 0; e < 8; ++e) {
        o0[e] = f2b(xs[pp * 261 + c0 + e] * rs);
        o1[e] = f2b(xs[pp * 261 + c0 + 8 + e] * rs);
      }
      u16* dst = &xnT[(size_t)(b * NPIX + p0 + pp) * CDIM + c0];
      *(u16x8*)dst = o0;
      *(u16x8*)(dst + 8) = o1;
    }
  }
}

// ---------------- Kernel 2: QKV projection GEMM, 128x128 tile -------------------
// C[p][o] = sum_c xnT[p][c] * wb[o][c];  grid (36, 12), block 512 (8 waves x 16 rows)
__global__ __launch_bounds__(512) void k_qkv(
    const u16* __restrict__ xnT, const u16* __restrict__ wb,
    u16* __restrict__ q, u16* __restrict__ kk, u16* __restrict__ vT)
{
  __shared__ __align__(16) u16 bs[128 * 256];  // 64KB, [row][col ^ (row&7)*8]
  const int t = threadIdx.x, w = t >> 6, l = t & 63, li = l & 15, kg = l >> 4;
  const int m0 = blockIdx.x * 128 + w * 16;
  const int n0 = blockIdx.y * 128;
  {
    const int brow = t >> 2, bcs = (t & 3) * 64;
    const int bsw = (brow & 7) * 8;
    const u16* wsrc = wb + (size_t)(n0 + brow) * CDIM + bcs;
#pragma unroll
    for (int j = 0; j < 8; ++j) {
      const u16x8 v = *(const u16x8*)&wsrc[j * 8];
      *(u16x8*)&bs[brow * 256 + ((bcs + j * 8) ^ bsw)] = v;
    }
  }
  const u16* ap = xnT + (size_t)(m0 + li) * CDIM + kg * 8;
  const int lsw = (li & 7) * 8;
  f32x4 acc[8];
#pragma unroll
  for (int cf = 0; cf < 8; ++cf) { f32x4 z = {0.f,0.f,0.f,0.f}; acc[cf] = z; }
  __syncthreads();
#pragma unroll
  for (int ks = 0; ks < 8; ++ks) {
    const bf16x8 af = *(const bf16x8*)(ap + ks * 32);
#pragma unroll
    for (int cf = 0; cf < 8; ++cf) {
      const int row = cf * 16 + li;
      const bf16x8 bfr = *(const bf16x8*)&bs[row * 256 + ((ks * 32 + kg * 8) ^ lsw)];
      acc[cf] = __builtin_amdgcn_mfma_f32_16x16x32_bf16(af, bfr, acc[cf], 0, 0, 0);
    }
  }
  const int bb = (m0 >= NPIX) ? 1 : 0;
  const int plbase = m0 - bb * NPIX + kg * 4;
#pragma unroll
  for (int cf = 0; cf < 8; ++cf) {
    const int o0f = n0 + cf * 16;          // uniform over lanes
    const int r = o0f >> 9, oo = o0f & 511, h = oo >> 6, d = (oo & 63) + li;
    if (r == 0) {
      u16* base = q + ((size_t)(bb * NHEAD + h) * NPIX + plbase) * DH + d;
#pragma unroll
      for (int rr = 0; rr < 4; ++rr) base[(size_t)rr * DH] = f2b(acc[cf][rr]);
    } else if (r == 1) {
      u16* base = kk + ((size_t)(bb * NHEAD + h) * NKV + NMEM + plbase) * DH + d;
#pragma unroll
      for (int rr = 0; rr < 4; ++rr) base[(size_t)rr * DH] = f2b(acc[cf][rr]);
    } else {
      u16x4 pk;
#pragma unroll
      for (int rr = 0; rr < 4; ++rr) pk[rr] = f2b(acc[cf][rr]);
      *(u16x4*)&vT[(((size_t)(bb * NHEAD + h)) * DH + d) * NKVP + NMEM + plbase] = pk;
    }
  }
}

// ---------------- Kernel 3: flash attention, balanced grid ----------------------
// grid 768 (XCD-pinned, EXACTLY 3 blocks/CU); block 384 = 6 waves:
// (qsub 0..2, 16q each = 48 q-rows/block) x (kv-half 0..1, 19/18 tiles).
// Per-wave machinery, barrier/prefetch order (R5-proven), kv-split combine all
// identical to R13. Staging by threads 0..255 (R10-proven 128-thr/half geometry).
__global__ __launch_bounds__(384) void k_attn(
    const u16* __restrict__ q, const u16* __restrict__ kk, const u16* __restrict__ vT,
    u16* __restrict__ aoB)
{
  __shared__ __align__(16) char smem[46592];
  u16* kbuf = (u16*)smem;                    // [2][64*64], swizzled (16KB)
  u16* vbuf = (u16*)(smem + 16384);          // [2][64*64], swizzled (16KB)
  u16* ps   = (u16*)(smem + 32768);          // [6][16*72] (13.5KB)
  float* accbuf = (float*)smem;              // epilogue overlay [48][67]
  float* mlbuf  = (float*)(smem + 17152);    // epilogue overlay [48][2]
  const int t = threadIdx.x;
  const int w = t >> 6, l = t & 63;
  const int hf = (w >= 3) ? 1 : 0;
  const int qsub = w - hf * 3;               // 0..2
  const int li = l & 15, kg = l >> 4;
  // XCD-aware decode: id&7 -> XCD; each XCD owns 2 heads (K/V L2-resident)
  const int id = blockIdx.x;
  const int xcd = id & 7, slot = id >> 3;    // slot 0..95
  const int yl = (slot >= 48) ? 1 : 0;
  const int xq = slot - yl * 48;             // 0..47
  const int bh = xcd * 2 + yl;
  const int b = bh >> 3, hh = bh & 7;
  const int qrow0 = xq * 48 + qsub * 16;
  const u16* qp = q + ((size_t)bh * NPIX + qrow0) * DH;
  const u16* kp = kk + (size_t)bh * NKV * DH;
  const u16* vp = vT + (size_t)bh * DH * NKVP;

  // Q B-fragment (persistent): lane (li,kg) holds Q[q=li][d=kg*8+e]
  const bf16x8 bq0 = *(const bf16x8*)&qp[li * DH + kg * 8];
  const bf16x8 bq1 = *(const bf16x8*)&qp[li * DH + 32 + kg * 8];

  // staging (threads 0..255 only): t<128 -> half 0, 128..255 -> half 1.
  // thread covers row srow (0..63), 32 contiguous u16 at sc (4 chunks of 8).
  const int hft = (t >> 7) & 1;
  const int tt = t & 127;
  const int srow = tt >> 1;                  // 0..63
  const int sc = (tt & 1) * 32;              // u16 units
  const int ssw = (srow & 7) * 8;
  const int sbase = hft * KVSPLIT;
  u16* kdst = &kbuf[hft * 4096 + srow * 64];
  u16* vdst = &vbuf[hft * 4096 + srow * 64];

  f32x4 acc[4];
#pragma unroll
  for (int df = 0; df < 4; ++df) { f32x4 z = {0.f,0.f,0.f,0.f}; acc[df] = z; }
  float m = -1e30f, lsum = 0.f;   // for q = li (uniform across kg)
  const int cbase0 = hf * KVSPLIT;

  // prologue: tile 0 of this half into regs (stagers only)
  u16x8 rk[4], rv[4];
  if (t < 256) {
    int kr = sbase + srow; if (kr > NKV - 1) kr = NKV - 1;
#pragma unroll
    for (int j = 0; j < 4; ++j) {
      rk[j] = *(const u16x8*)&kp[(size_t)kr * DH + sc + j * 8];
      rv[j] = *(const u16x8*)&vp[(size_t)srow * NKVP + sbase + sc + j * 8];
    }
  }

  const int NT = 19;
#pragma unroll 1
  for (int i = 0; i < NT; ++i) {
    __syncthreads();   // all waves done reading kbuf/vbuf from previous tile
    if (t < 256) {
#pragma unroll
      for (int j = 0; j < 4; ++j) {
        *(u16x8*)&kdst[(sc + j * 8) ^ ssw] = rk[j];
        *(u16x8*)&vdst[(sc + j * 8) ^ ssw] = rv[j];
      }
      if (i + 1 < NT) {   // prefetch between barriers (R5-proven ordering)
        const int nb = sbase + (i + 1) * 64;
        const int snb = (nb > NKVP - 64) ? (NKVP - 64) : nb;   // V clamp
        int kr = nb + srow; if (kr > NKV - 1) kr = NKV - 1;
#pragma unroll
        for (int j = 0; j < 4; ++j) {
          rk[j] = *(const u16x8*)&kp[(size_t)kr * DH + sc + j * 8];
          rv[j] = *(const u16x8*)&vp[(size_t)srow * NKVP + snb + sc + j * 8];
        }
      }
    }
    __syncthreads();   // kbuf/vbuf ready
    const int kbase = cbase0 + i * 64;
    if (kbase < NKV) {     // wave-uniform; hf=1 skips its dummy 19th tile
      const bool lastt = (kbase + 64 > NKV);
      const u16* kb = &kbuf[hf * 4096];
      const u16* vb = &vbuf[hf * 4096];
      // S^T = K . Q^T : lane holds kv=kg*4+r, q=li
      f32x4 s[4];
#pragma unroll
      for (int jf = 0; jf < 4; ++jf) {
        const int row = jf * 16 + li;
        const int rsw = (row & 7) * 8;
        const bf16x8 ak0 = *(const bf16x8*)&kb[row * 64 + ((kg * 8) ^ rsw)];
        const bf16x8 ak1 = *(const bf16x8*)&kb[row * 64 + ((32 + kg * 8) ^ rsw)];
        f32x4 sf = {0.f, 0.f, 0.f, 0.f};
        sf = __builtin_amdgcn_mfma_f32_16x16x32_bf16(ak0, bq0, sf, 0, 0, 0);
        sf = __builtin_amdgcn_mfma_f32_16x16x32_bf16(ak1, bq1, sf, 0, 0, 0);
        s[jf] = sf;
      }
      if (lastt) {
#pragma unroll
        for (int jf = 0; jf < 4; ++jf)
#pragma unroll
          for (int r = 0; r < 4; ++r)
            if (kbase + jf * 16 + kg * 4 + r >= NKV) s[jf][r] = -1e30f;
      }
      // row max (row = q = li)
      float pmax = fmaxf(fmaxf(fmaxf(s[0][0], s[0][1]), fmaxf(s[0][2], s[0][3])),
                         fmaxf(fmaxf(s[1][0], s[1][1]), fmaxf(s[1][2], s[1][3])));
      pmax = fmaxf(pmax, fmaxf(fmaxf(fmaxf(s[2][0], s[2][1]), fmaxf(s[2][2], s[2][3])),
                               fmaxf(fmaxf(s[3][0], s[3][1]), fmaxf(s[3][2], s[3][3]))));
      pmax = fmaxf(pmax, __shfl_xor(pmax, 16));
      pmax = fmaxf(pmax, __shfl_xor(pmax, 32));
      // defer-max (THR=8 in log2 units)
      if (__any(pmax > m + 8.0f)) {
        const float mn = fmaxf(m, pmax);
        const float al = EXP2(m - mn);
        m = mn;
        lsum *= al;
        float a4[4];
#pragma unroll
        for (int r = 0; r < 4; ++r) a4[r] = __shfl(al, (l & 48) | (kg * 4 + r));
#pragma unroll
        for (int df = 0; df < 4; ++df)
#pragma unroll
          for (int r = 0; r < 4; ++r) acc[df][r] *= a4[r];
      }
      // exp2 + per-lane sum + pack to bf16 + per-wave LDS
#pragma unroll
      for (int jf = 0; jf < 4; ++jf) {
        u32x2 wp;
#pragma unroll
        for (int rp = 0; rp < 2; ++rp) {
          const float e0 = EXP2(s[jf][rp * 2 + 0] - m);
          const float e1 = EXP2(s[jf][rp * 2 + 1] - m);
          lsum += e0 + e1;
          unsigned pk;
          asm("v_cvt_pk_bf16_f32 %0, %1, %2" : "=v"(pk) : "v"(e0), "v"(e1));
          wp[rp] = pk;
        }
        *(u32x2*)&ps[w * 1152 + li * 72 + jf * 16 + kg * 4] = wp;
      }
      asm volatile("s_waitcnt lgkmcnt(0)" ::: "memory");
      __builtin_amdgcn_sched_barrier(0);
      // PV: A = P[q=li][kv], B = V^T rows from swizzled LDS
      const bf16x8 ap0 = *(const bf16x8*)&ps[w * 1152 + li * 72 + kg * 8];
      const bf16x8 ap1 = *(const bf16x8*)&ps[w * 1152 + li * 72 + 32 + kg * 8];
#pragma unroll
      for (int df = 0; df < 4; ++df) {
        const int row = df * 16 + li;
        const int rsw = (row & 7) * 8;
        const bf16x8 bv0 = *(const bf16x8*)&vb[row * 64 + ((kg * 8) ^ rsw)];
        const bf16x8 bv1 = *(const bf16x8*)&vb[row * 64 + ((32 + kg * 8) ^ rsw)];
        acc[df] = __builtin_amdgcn_mfma_f32_16x16x32_bf16(ap0, bv0, acc[df], 0, 0, 0);
        acc[df] = __builtin_amdgcn_mfma_f32_16x16x32_bf16(ap1, bv1, acc[df], 0, 0, 0);
      }
    }
  }
  // final per-row l; combine the two halves in LDS
  lsum += __shfl_xor(lsum, 16);
  lsum += __shfl_xor(lsum, 32);
  float m4[4], l4[4];
#pragma unroll
  for (int r = 0; r < 4; ++r) {
    const int src = (l & 48) | (kg * 4 + r);
    m4[r] = __shfl(m, src);
    l4[r] = __shfl(lsum, src);
  }
  __syncthreads();    // protect overlay region (kbuf) from in-loop readers
  if (hf == 1) {
#pragma unroll
    for (int df = 0; df < 4; ++df)
#pragma unroll
      for (int r = 0; r < 4; ++r)
        accbuf[(qsub * 16 + kg * 4 + r) * 67 + df * 16 + li] = acc[df][r];
    if (kg == 0) {
      mlbuf[(qsub * 16 + li) * 2 + 0] = m;
      mlbuf[(qsub * 16 + li) * 2 + 1] = lsum;
    }
  }
  __syncthreads();
  if (hf == 0) {
    float f0[4], f1[4], rL[4];
#pragma unroll
    for (int r = 0; r < 4; ++r) {
      const float m1 = mlbuf[(qsub * 16 + kg * 4 + r) * 2 + 0];
      const float l1 = mlbuf[(qsub * 16 + kg * 4 + r) * 2 + 1];
      const float M = fmaxf(m4[r], m1);
      f0[r] = EXP2(m4[r] - M);
      f1[r] = EXP2(m1 - M);
      rL[r] = __builtin_amdgcn_rcpf(l4[r] * f0[r] + l1 * f1[r]);
    }
#pragma unroll
    for (int df = 0; df < 4; ++df)
#pragma unroll
      for (int r = 0; r < 4; ++r) {
        const float a1 = accbuf[(qsub * 16 + kg * 4 + r) * 67 + df * 16 + li];
        const float o = (acc[df][r] * f0[r] + a1 * f1[r]) * rL[r];
        aoB[((size_t)b * NPIX + qrow0 + kg * 4 + r) * HID + hh * DH + df * 16 + li] = f2b(o);
      }
  }
}

// ---------------- Kernel 4: out projection GEMM, 64x64 tile, B in LDS -----------
// out[b][o][p] = sum_c aoB[p][c] * wob[o][c];  grid (72, 4), block 256
__global__ __launch_bounds__(256) void k_outg(
    const u16* __restrict__ aoB, const u16* __restrict__ wob, float* __restrict__ out)
{
  __shared__ __align__(16) u16 bs[64 * 512];   // 64KB, [row][col ^ (row&7)*8]
  const int t = threadIdx.x, w = t >> 6, l = t & 63, li = l & 15, kg = l >> 4;
  const int m0 = blockIdx.x * 64 + w * 16;
  const int n0 = blockIdx.y * 64;
  {
    const int brow = t >> 2, bcs = (t & 3) * 128;
    const int bsw = (brow & 7) * 8;
    const u16* wsrc = wob + (size_t)(n0 + brow) * HID + bcs;
#pragma unroll
    for (int j = 0; j < 16; ++j) {
      const u16x8 v = *(const u16x8*)&wsrc[j * 8];
      *(u16x8*)&bs[brow * 512 + ((bcs + j * 8) ^ bsw)] = v;
    }
  }
  const u16* ap = aoB + (size_t)(m0 + li) * HID + kg * 8;
  const int lsw = (li & 7) * 8;
  f32x4 acc[4];
#pragma unroll
  for (int cf = 0; cf < 4; ++cf) { f32x4 z = {0.f,0.f,0.f,0.f}; acc[cf] = z; }
  __syncthreads();
#pragma unroll
  for (int ks = 0; ks < 16; ++ks) {
    const bf16x8 af = *(const bf16x8*)(ap + ks * 32);
#pragma unroll
    for (int cf = 0; cf < 4; ++cf) {
      const int row = cf * 16 + li;
      const bf16x8 bf = *(const bf16x8*)&bs[row * 512 + ((ks * 32 + kg * 8) ^ lsw)];
      acc[cf] = __builtin_amdgcn_mfma_f32_16x16x32_bf16(af, bf, acc[cf], 0, 0, 0);
    }
  }
  const int bb = (m0 >= NPIX) ? 1 : 0;
  const int pl = m0 - bb * NPIX + kg * 4;
#pragma unroll
  for (int cf = 0; cf < 4; ++cf) {
    const int o = n0 + cf * 16 + li;
    *(f32x4*)&out[((size_t)(bb * CDIM + o)) * NPIX + pl] = acc[cf];
  }
}

extern "C" void kernel_launch(void* const* d_in, const int* in_sizes, int n_in,
                              void* d_out, int out_size, void* d_ws, size_t ws_size,
                              hipStream_t stream)
{
  const float* x      = (const float*)d_in[0];
  const float* gamma  = (const float*)d_in[1];
  const float* mem_kv = (const float*)d_in[2];
  const float* wqkv   = (const float*)d_in[3];
  const float* wout   = (const float*)d_in[4];
  float* out = (float*)d_out;
  char* ws = (char*)d_ws;
  const size_t XNT = (size_t)BATCH * NPIX * CDIM * sizeof(u16);        // 2,359,296
  const size_t WB  = (size_t)(WQKV_E + WOUT_E) * sizeof(u16);          // 1,048,576
  const size_t QB  = (size_t)BATCH * NHEAD * NPIX * DH * sizeof(u16);  // 4,718,592
  const size_t KB  = (size_t)BATCH * NHEAD * NKV  * DH * sizeof(u16);  // 4,726,784
  const size_t VTB = (size_t)BATCH * NHEAD * DH * NKVP * sizeof(u16);  // 4,849,664
  u16* xnT = (u16*)ws;
  u16* wb  = (u16*)(ws + XNT);
  u16* q   = (u16*)(ws + XNT + WB);
  u16* kk  = (u16*)(ws + XNT + WB + QB);
  u16* vT  = (u16*)(ws + XNT + WB + QB + KB);
  u16* aoB = (u16*)(ws + XNT + WB + QB + KB + VTB);  // + 4,718,592 -> ~21.4 MB

  k_prep<<<dim3(624), dim3(256), 0, stream>>>(wqkv, wout, gamma, mem_kv, x,
                                              wb, kk, vT, xnT);
  k_qkv<<<dim3(36, 12), dim3(512), 0, stream>>>(xnT, wb, q, kk, vT);
  k_attn<<<dim3(768), dim3(384), 0, stream>>>(q, kk, vT, aoB);
  k_outg<<<dim3(72, 4), dim3(256), 0, stream>>>(aoB, wb + WQKV_E, out);
}

// Round 15
// 87.716 us; speedup vs baseline: 1.0422x; 1.0422x over previous
//
#include <hip/hip_runtime.h>

#define BATCH 2
#define CDIM 256
#define NPIX 2304      // 48*48
#define NHEAD 8
#define DH 64
#define HID 512
#define NMEM 4
#define NKV 2308       // NMEM + NPIX
#define NKVP 2368      // NKV padded to multiple of 64 (zeroed pad)
#define QSCALE 0.125f  // 64^-0.5
#define LOG2E 1.4426950408889634f
#define WQKV_E 393216  // 1536*256
#define WOUT_E 131072  // 256*512
#define KVSPLIT 1216   // half 0: kv 0..1215 (19 tiles); half 1: 1216..2367 (18)

typedef float f32x4 __attribute__((ext_vector_type(4)));
typedef __bf16 bf16x8 __attribute__((ext_vector_type(8)));
typedef unsigned short u16;
typedef u16 u16x4 __attribute__((ext_vector_type(4)));
typedef u16 u16x8 __attribute__((ext_vector_type(8)));
typedef unsigned u32x2 __attribute__((ext_vector_type(2)));

#if __has_builtin(__builtin_amdgcn_exp2f)
#define EXP2(x) __builtin_amdgcn_exp2f(x)
#else
#define EXP2(x) exp2f(x)
#endif

static __device__ __forceinline__ u16 f2b(float f) {
  union { float f; unsigned u; } a; a.f = f;
  unsigned u = a.u;
  u += 0x7fffu + ((u >> 16) & 1u);   // RNE
  return (u16)(u >> 16);
}
static __device__ __forceinline__ float b2f(u16 b) {
  union { float f; unsigned u; } a; a.u = ((unsigned)b) << 16; return a.f;
}

// ---------------- Kernel 1: merged prep + RMSNorm ------------------------------
// blocks 0..255: wb = bf16(wqkv * (1+gamma) [* QSCALE*LOG2E on q rows]) | bf16(wout)
// blocks 256..271: mem kv tokens; 272..335: zero vT pad; 336..623: RMSNorm->xnT
__global__ __launch_bounds__(256) void k_prep(
    const float* __restrict__ wqkv, const float* __restrict__ wout,
    const float* __restrict__ gamma, const float* __restrict__ mem_kv,
    const float* __restrict__ x,
    u16* __restrict__ wb, u16* __restrict__ kk, u16* __restrict__ vT,
    u16* __restrict__ xnT)
{
  __shared__ float xs[16 * 261];
  __shared__ float red[16][17];
  __shared__ float rsh[16];
  const int blk = blockIdx.x, t = threadIdx.x;
  if (blk < 256) {
    const int i0 = (blk * 256 + t) * 8;
    u16x8 o;
    if (i0 < WQKV_E) {
      const float sc = ((i0 >> 8) < 512) ? QSCALE * LOG2E : 1.0f;
      const int c0 = i0 & 255;
      const f32x4 a = *(const f32x4*)&wqkv[i0];
      const f32x4 b = *(const f32x4*)&wqkv[i0 + 4];
      const f32x4 g0 = *(const f32x4*)&gamma[c0];
      const f32x4 g1 = *(const f32x4*)&gamma[c0 + 4];
#pragma unroll
      for (int e = 0; e < 4; ++e) {
        o[e]     = f2b(a[e] * sc * (1.0f + g0[e]));
        o[e + 4] = f2b(b[e] * sc * (1.0f + g1[e]));
      }
    } else {
      const f32x4 a = *(const f32x4*)&wout[i0 - WQKV_E];
      const f32x4 b = *(const f32x4*)&wout[i0 - WQKV_E + 4];
#pragma unroll
      for (int e = 0; e < 4; ++e) { o[e] = f2b(a[e]); o[e + 4] = f2b(b[e]); }
    }
    *(u16x8*)&wb[i0] = o;
  } else if (blk < 272) {
    const int idx = (blk - 256) * 256 + t;   // 0..4095 = b,h,m,d
    const int d = idx & 63;
    const int m = (idx >> 6) & 3;
    const int h = (idx >> 8) & 7;
    const int b = idx >> 11;
    const float mk = mem_kv[((size_t)h * NMEM + m) * DH + d];
    const float mv = mem_kv[(((size_t)NHEAD + h) * NMEM + m) * DH + d];
    kk[(((size_t)(b * NHEAD + h)) * NKV + m) * DH + d] = f2b(mk);
    vT[(((size_t)(b * NHEAD + h)) * DH + d) * NKVP + m] = f2b(mv);
  } else if (blk < 336) {
    const int gid = (blk - 272) * 256 + t;   // 0..16383
    const int row = gid >> 4;                 // bh*64+d
    const int c0 = (gid & 15) * 4 + 2304;
    u16x4 z = {0, 0, 0, 0};
    *(u16x4*)&vT[(size_t)row * NKVP + c0] = z;
  } else {
    // RMSNorm -> xn^T bf16 [b*p][c] (gamma folded into weights)
    const int blk2 = blk - 336;
    const int b = blk2 / 144;
    const int p0 = (blk2 % 144) * 16;
    const int px = t & 15, cg = t >> 4;
    const float* xb = x + (size_t)b * CDIM * NPIX + p0 + px;
    float ssq = 0.f;
#pragma unroll
    for (int i = 0; i < 16; ++i) {
      const int c = cg * 16 + i;
      const float v = xb[(size_t)c * NPIX];
      xs[px * 261 + c] = v;
      ssq += v * v;
    }
    red[px][cg] = ssq;
    __syncthreads();
    if (t < 16) {
      float s = 0.f;
#pragma unroll
      for (int i = 0; i < 16; ++i) s += red[t][i];
      rsh[t] = 16.0f / fmaxf(sqrtf(s), 1e-12f);   // sqrt(CDIM)=16
    }
    __syncthreads();
    {
      const int pp = t >> 4, c0 = (t & 15) * 16;
      const float rs = rsh[pp];
      u16x8 o0, o1;
#pragma unroll
      for (int e = 0; e < 8; ++e) {
        o0[e] = f2b(xs[pp * 261 + c0 + e] * rs);
        o1[e] = f2b(xs[pp * 261 + c0 + 8 + e] * rs);
      }
      u16* dst = &xnT[(size_t)(b * NPIX + p0 + pp) * CDIM + c0];
      *(u16x8*)dst = o0;
      *(u16x8*)(dst + 8) = o1;
    }
  }
}

// ---------------- Kernel 2: QKV projection GEMM, 128x128 tile -------------------
// C[p][o] = sum_c xnT[p][c] * wb[o][c];  grid (36, 12), block 512 (8 waves x 16 rows)
__global__ __launch_bounds__(512) void k_qkv(
    const u16* __restrict__ xnT, const u16* __restrict__ wb,
    u16* __restrict__ q, u16* __restrict__ kk, u16* __restrict__ vT)
{
  __shared__ __align__(16) u16 bs[128 * 256];  // 64KB, [row][col ^ (row&7)*8]
  const int t = threadIdx.x, w = t >> 6, l = t & 63, li = l & 15, kg = l >> 4;
  const int m0 = blockIdx.x * 128 + w * 16;
  const int n0 = blockIdx.y * 128;
  {
    const int brow = t >> 2, bcs = (t & 3) * 64;
    const int bsw = (brow & 7) * 8;
    const u16* wsrc = wb + (size_t)(n0 + brow) * CDIM + bcs;
#pragma unroll
    for (int j = 0; j < 8; ++j) {
      const u16x8 v = *(const u16x8*)&wsrc[j * 8];
      *(u16x8*)&bs[brow * 256 + ((bcs + j * 8) ^ bsw)] = v;
    }
  }
  const u16* ap = xnT + (size_t)(m0 + li) * CDIM + kg * 8;
  const int lsw = (li & 7) * 8;
  f32x4 acc[8];
#pragma unroll
  for (int cf = 0; cf < 8; ++cf) { f32x4 z = {0.f,0.f,0.f,0.f}; acc[cf] = z; }
  __syncthreads();
#pragma unroll
  for (int ks = 0; ks < 8; ++ks) {
    const bf16x8 af = *(const bf16x8*)(ap + ks * 32);
#pragma unroll
    for (int cf = 0; cf < 8; ++cf) {
      const int row = cf * 16 + li;
      const bf16x8 bfr = *(const bf16x8*)&bs[row * 256 + ((ks * 32 + kg * 8) ^ lsw)];
      acc[cf] = __builtin_amdgcn_mfma_f32_16x16x32_bf16(af, bfr, acc[cf], 0, 0, 0);
    }
  }
  const int bb = (m0 >= NPIX) ? 1 : 0;
  const int plbase = m0 - bb * NPIX + kg * 4;
#pragma unroll
  for (int cf = 0; cf < 8; ++cf) {
    const int o0f = n0 + cf * 16;          // uniform over lanes
    const int r = o0f >> 9, oo = o0f & 511, h = oo >> 6, d = (oo & 63) + li;
    if (r == 0) {
      u16* base = q + ((size_t)(bb * NHEAD + h) * NPIX + plbase) * DH + d;
#pragma unroll
      for (int rr = 0; rr < 4; ++rr) base[(size_t)rr * DH] = f2b(acc[cf][rr]);
    } else if (r == 1) {
      u16* base = kk + ((size_t)(bb * NHEAD + h) * NKV + NMEM + plbase) * DH + d;
#pragma unroll
      for (int rr = 0; rr < 4; ++rr) base[(size_t)rr * DH] = f2b(acc[cf][rr]);
    } else {
      u16x4 pk;
#pragma unroll
      for (int rr = 0; rr < 4; ++rr) pk[rr] = f2b(acc[cf][rr]);
      *(u16x4*)&vT[(((size_t)(bb * NHEAD + h)) * DH + d) * NKVP + NMEM + plbase] = pk;
    }
  }
}

// ---------------- Kernel 3: flash attention (R5/R13 structure — best measured) --
// grid 576 (XCD-pinned); block 512 = 8 waves: (qsub 0..3, 16q) x (kv-half 0..1).
// Prefetch issued between barriers; std barriers; per-wave in-LDS P; kv-split
// combine with stride-67 f32 scalar loads (alignment-safe).
__global__ __launch_bounds__(512) void k_attn(
    const u16* __restrict__ q, const u16* __restrict__ kk, const u16* __restrict__ vT,
    u16* __restrict__ aoB)
{
  __shared__ __align__(16) char smem[51200];
  u16* kbuf = (u16*)smem;                    // [2][64*64], swizzled
  u16* vbuf = (u16*)(smem + 16384);          // [2][64*64], swizzled
  u16* ps   = (u16*)(smem + 32768);          // [8][16*72]
  float* accbuf = (float*)smem;              // epilogue overlay [4][16][67]
  float* mlbuf  = (float*)(smem + 17152);    // epilogue overlay [4][16][2]
  const int t = threadIdx.x;
  const int w = t >> 6, l = t & 63;
  const int qsub = w & 3, hf = w >> 2;
  const int li = l & 15, kg = l >> 4;
  // XCD-aware decode: id&7 -> XCD; each XCD owns 2 heads (K/V L2-resident)
  const int id = blockIdx.x;
  const int xcd = id & 7, slot = id >> 3;    // slot 0..71
  const int yl = (slot >= 36) ? 1 : 0;
  const int xq = slot - yl * 36;
  const int bh = xcd * 2 + yl;
  const int b = bh >> 3, hh = bh & 7;
  const int qrow0 = xq * 64 + qsub * 16;
  const u16* qp = q + ((size_t)bh * NPIX + qrow0) * DH;
  const u16* kp = kk + (size_t)bh * NKV * DH;
  const u16* vp = vT + (size_t)bh * DH * NKVP;

  // Q B-fragment (persistent): lane (li,kg) holds Q[q=li][d=kg*8+e]
  const bf16x8 bq0 = *(const bf16x8*)&qp[li * DH + kg * 8];
  const bf16x8 bq1 = *(const bf16x8*)&qp[li * DH + 32 + kg * 8];

  // staging geometry: threads t<256 stage half 0, t>=256 stage half 1
  const int hft = t >> 8;
  const int tt = t & 255;
  const int srow = tt >> 3;                  // 0..31
  const int scol = (tt & 7) * 8;             // u16 units
  const int ssw = (srow & 7) * 8;
  const int sbase = hft * KVSPLIT;
  u16* kdst0 = &kbuf[hft * 4096 + srow * 64 + (scol ^ ssw)];
  u16* kdst1 = &kbuf[hft * 4096 + (srow + 32) * 64 + (scol ^ ssw)];
  u16* vdst0 = &vbuf[hft * 4096 + srow * 64 + (scol ^ ssw)];
  u16* vdst1 = &vbuf[hft * 4096 + (srow + 32) * 64 + (scol ^ ssw)];

  f32x4 acc[4];
#pragma unroll
  for (int df = 0; df < 4; ++df) { f32x4 z = {0.f,0.f,0.f,0.f}; acc[df] = z; }
  float m = -1e30f, lsum = 0.f;   // for q = li (uniform across kg)
  const int cbase0 = hf * KVSPLIT;

  u16x8 rk0, rk1, rv0, rv1;
  // prologue: load tile 0 of this half into regs
  rk0 = *(const u16x8*)&kp[(size_t)(sbase + srow) * DH + scol];
  rk1 = *(const u16x8*)&kp[(size_t)(sbase + srow + 32) * DH + scol];
  rv0 = *(const u16x8*)&vp[(size_t)srow * NKVP + sbase + scol];
  rv1 = *(const u16x8*)&vp[(size_t)(srow + 32) * NKVP + sbase + scol];

  const int NT = 19;
#pragma unroll 1
  for (int i = 0; i < NT; ++i) {
    __syncthreads();   // all waves done reading kbuf/vbuf from previous tile
    *(u16x8*)kdst0 = rk0;
    *(u16x8*)kdst1 = rk1;
    *(u16x8*)vdst0 = rv0;
    *(u16x8*)vdst1 = rv1;
    if (i + 1 < NT) {
      int nb = sbase + (i + 1) * 64;
      int snb = (nb > NKVP - 64) ? (NKVP - 64) : nb;   // V clamp (hf=1 last iter)
      int kr0 = nb + srow;      if (kr0 > NKV - 1) kr0 = NKV - 1;
      int kr1 = nb + srow + 32; if (kr1 > NKV - 1) kr1 = NKV - 1;
      rk0 = *(const u16x8*)&kp[(size_t)kr0 * DH + scol];
      rk1 = *(const u16x8*)&kp[(size_t)kr1 * DH + scol];
      rv0 = *(const u16x8*)&vp[(size_t)srow * NKVP + snb + scol];
      rv1 = *(const u16x8*)&vp[(size_t)(srow + 32) * NKVP + snb + scol];
    }
    __syncthreads();   // kbuf/vbuf ready
    const int kbase = cbase0 + i * 64;
    if (kbase < NKV) {     // wave-uniform; hf=1 skips its dummy 19th tile
      const bool lastt = (kbase + 64 > NKV);
      const u16* kb = &kbuf[hf * 4096];
      const u16* vb = &vbuf[hf * 4096];
      // S^T = K . Q^T : lane holds kv=kg*4+r, q=li
      f32x4 s[4];
#pragma unroll
      for (int jf = 0; jf < 4; ++jf) {
        const int row = jf * 16 + li;
        const int rsw = (row & 7) * 8;
        const bf16x8 ak0 = *(const bf16x8*)&kb[row * 64 + ((kg * 8) ^ rsw)];
        const bf16x8 ak1 = *(const bf16x8*)&kb[row * 64 + ((32 + kg * 8) ^ rsw)];
        f32x4 sf = {0.f, 0.f, 0.f, 0.f};
        sf = __builtin_amdgcn_mfma_f32_16x16x32_bf16(ak0, bq0, sf, 0, 0, 0);
        sf = __builtin_amdgcn_mfma_f32_16x16x32_bf16(ak1, bq1, sf, 0, 0, 0);
        s[jf] = sf;
      }
      if (lastt) {
#pragma unroll
        for (int jf = 0; jf < 4; ++jf)
#pragma unroll
          for (int r = 0; r < 4; ++r)
            if (kbase + jf * 16 + kg * 4 + r >= NKV) s[jf][r] = -1e30f;
      }
      // row max (row = q = li)
      float pmax = fmaxf(fmaxf(fmaxf(s[0][0], s[0][1]), fmaxf(s[0][2], s[0][3])),
                         fmaxf(fmaxf(s[1][0], s[1][1]), fmaxf(s[1][2], s[1][3])));
      pmax = fmaxf(pmax, fmaxf(fmaxf(fmaxf(s[2][0], s[2][1]), fmaxf(s[2][2], s[2][3])),
                               fmaxf(fmaxf(s[3][0], s[3][1]), fmaxf(s[3][2], s[3][3]))));
      pmax = fmaxf(pmax, __shfl_xor(pmax, 16));
      pmax = fmaxf(pmax, __shfl_xor(pmax, 32));
      // defer-max (THR=8 in log2 units)
      if (__any(pmax > m + 8.0f)) {
        const float mn = fmaxf(m, pmax);
        const float al = EXP2(m - mn);
        m = mn;
        lsum *= al;
        float a4[4];
#pragma unroll
        for (int r = 0; r < 4; ++r) a4[r] = __shfl(al, (l & 48) | (kg * 4 + r));
#pragma unroll
        for (int df = 0; df < 4; ++df)
#pragma unroll
          for (int r = 0; r < 4; ++r) acc[df][r] *= a4[r];
      }
      // exp2 + per-lane sum + pack to bf16 + per-wave LDS
#pragma unroll
      for (int jf = 0; jf < 4; ++jf) {
        u32x2 wp;
#pragma unroll
        for (int rp = 0; rp < 2; ++rp) {
          const float e0 = EXP2(s[jf][rp * 2 + 0] - m);
          const float e1 = EXP2(s[jf][rp * 2 + 1] - m);
          lsum += e0 + e1;
          unsigned pk;
          asm("v_cvt_pk_bf16_f32 %0, %1, %2" : "=v"(pk) : "v"(e0), "v"(e1));
          wp[rp] = pk;
        }
        *(u32x2*)&ps[w * 1152 + li * 72 + jf * 16 + kg * 4] = wp;
      }
      asm volatile("s_waitcnt lgkmcnt(0)" ::: "memory");
      __builtin_amdgcn_sched_barrier(0);
      // PV: A = P[q=li][kv], B = V^T rows from swizzled LDS
      const bf16x8 ap0 = *(const bf16x8*)&ps[w * 1152 + li * 72 + kg * 8];
      const bf16x8 ap1 = *(const bf16x8*)&ps[w * 1152 + li * 72 + 32 + kg * 8];
#pragma unroll
      for (int df = 0; df < 4; ++df) {
        const int row = df * 16 + li;
        const int rsw = (row & 7) * 8;
        const bf16x8 bv0 = *(const bf16x8*)&vb[row * 64 + ((kg * 8) ^ rsw)];
        const bf16x8 bv1 = *(const bf16x8*)&vb[row * 64 + ((32 + kg * 8) ^ rsw)];
        acc[df] = __builtin_amdgcn_mfma_f32_16x16x32_bf16(ap0, bv0, acc[df], 0, 0, 0);
        acc[df] = __builtin_amdgcn_mfma_f32_16x16x32_bf16(ap1, bv1, acc[df], 0, 0, 0);
      }
    }
  }
  // final per-row l; combine the two halves in LDS
  lsum += __shfl_xor(lsum, 16);
  lsum += __shfl_xor(lsum, 32);
  float m4[4], l4[4];
#pragma unroll
  for (int r = 0; r < 4; ++r) {
    const int src = (l & 48) | (kg * 4 + r);
    m4[r] = __shfl(m, src);
    l4[r] = __shfl(lsum, src);
  }
  __syncthreads();    // protect overlay region (kbuf) from in-loop readers
  if (hf == 1) {
#pragma unroll
    for (int df = 0; df < 4; ++df)
#pragma unroll
      for (int r = 0; r < 4; ++r)
        accbuf[(qsub * 16 + kg * 4 + r) * 67 + df * 16 + li] = acc[df][r];
    if (kg == 0) {
      mlbuf[(qsub * 16 + li) * 2 + 0] = m;
      mlbuf[(qsub * 16 + li) * 2 + 1] = lsum;
    }
  }
  __syncthreads();
  if (hf == 0) {
    float f0[4], f1[4], rL[4];
#pragma unroll
    for (int r = 0; r < 4; ++r) {
      const float m1 = mlbuf[(qsub * 16 + kg * 4 + r) * 2 + 0];
      const float l1 = mlbuf[(qsub * 16 + kg * 4 + r) * 2 + 1];
      const float M = fmaxf(m4[r], m1);
      f0[r] = EXP2(m4[r] - M);
      f1[r] = EXP2(m1 - M);
      rL[r] = __builtin_amdgcn_rcpf(l4[r] * f0[r] + l1 * f1[r]);
    }
#pragma unroll
    for (int df = 0; df < 4; ++df)
#pragma unroll
      for (int r = 0; r < 4; ++r) {
        const float a1 = accbuf[(qsub * 16 + kg * 4 + r) * 67 + df * 16 + li];
        const float o = (acc[df][r] * f0[r] + a1 * f1[r]) * rL[r];
        aoB[((size_t)b * NPIX + qrow0 + kg * 4 + r) * HID + hh * DH + df * 16 + li] = f2b(o);
      }
  }
}

// ---------------- Kernel 4: out projection GEMM, 64x64 tile, B in LDS -----------
// out[b][o][p] = sum_c aoB[p][c] * wob[o][c];  grid (72, 4), block 256
__global__ __launch_bounds__(256) void k_outg(
    const u16* __restrict__ aoB, const u16* __restrict__ wob, float* __restrict__ out)
{
  __shared__ __align__(16) u16 bs[64 * 512];   // 64KB, [row][col ^ (row&7)*8]
  const int t = threadIdx.x, w = t >> 6, l = t & 63, li = l & 15, kg = l >> 4;
  const int m0 = blockIdx.x * 64 + w * 16;
  const int n0 = blockIdx.y * 64;
  {
    const int brow = t >> 2, bcs = (t & 3) * 128;
    const int bsw = (brow & 7) * 8;
    const u16* wsrc = wob + (size_t)(n0 + brow) * HID + bcs;
#pragma unroll
    for (int j = 0; j < 16; ++j) {
      const u16x8 v = *(const u16x8*)&wsrc[j * 8];
      *(u16x8*)&bs[brow * 512 + ((bcs + j * 8) ^ bsw)] = v;
    }
  }
  const u16* ap = aoB + (size_t)(m0 + li) * HID + kg * 8;
  const int lsw = (li & 7) * 8;
  f32x4 acc[4];
#pragma unroll
  for (int cf = 0; cf < 4; ++cf) { f32x4 z = {0.f,0.f,0.f,0.f}; acc[cf] = z; }
  __syncthreads();
#pragma unroll
  for (int ks = 0; ks < 16; ++ks) {
    const bf16x8 af = *(const bf16x8*)(ap + ks * 32);
#pragma unroll
    for (int cf = 0; cf < 4; ++cf) {
      const int row = cf * 16 + li;
      const bf16x8 bf = *(const bf16x8*)&bs[row * 512 + ((ks * 32 + kg * 8) ^ lsw)];
      acc[cf] = __builtin_amdgcn_mfma_f32_16x16x32_bf16(af, bf, acc[cf], 0, 0, 0);
    }
  }
  const int bb = (m0 >= NPIX) ? 1 : 0;
  const int pl = m0 - bb * NPIX + kg * 4;
#pragma unroll
  for (int cf = 0; cf < 4; ++cf) {
    const int o = n0 + cf * 16 + li;
    *(f32x4*)&out[((size_t)(bb * CDIM + o)) * NPIX + pl] = acc[cf];
  }
}

extern "C" void kernel_launch(void* const* d_in, const int* in_sizes, int n_in,
                              void* d_out, int out_size, void* d_ws, size_t ws_size,
                              hipStream_t stream)
{
  const float* x      = (const float*)d_in[0];
  const float* gamma  = (const float*)d_in[1];
  const float* mem_kv = (const float*)d_in[2];
  const float* wqkv   = (const float*)d_in[3];
  const float* wout   = (const float*)d_in[4];
  float* out = (float*)d_out;
  char* ws = (char*)d_ws;
  const size_t XNT = (size_t)BATCH * NPIX * CDIM * sizeof(u16);        // 2,359,296
  const size_t WB  = (size_t)(WQKV_E + WOUT_E) * sizeof(u16);          // 1,048,576
  const size_t QB  = (size_t)BATCH * NHEAD * NPIX * DH * sizeof(u16);  // 4,718,592
  const size_t KB  = (size_t)BATCH * NHEAD * NKV  * DH * sizeof(u16);  // 4,726,784
  const size_t VTB = (size_t)BATCH * NHEAD * DH * NKVP * sizeof(u16);  // 4,849,664
  u16* xnT = (u16*)ws;
  u16* wb  = (u16*)(ws + XNT);
  u16* q   = (u16*)(ws + XNT + WB);
  u16* kk  = (u16*)(ws + XNT + WB + QB);
  u16* vT  = (u16*)(ws + XNT + WB + QB + KB);
  u16* aoB = (u16*)(ws + XNT + WB + QB + KB + VTB);  // + 4,718,592 -> ~21.4 MB

  k_prep<<<dim3(624), dim3(256), 0, stream>>>(wqkv, wout, gamma, mem_kv, x,
                                              wb, kk, vT, xnT);
  k_qkv<<<dim3(36, 12), dim3(512), 0, stream>>>(xnT, wb, q, kk, vT);
  k_attn<<<dim3(576), dim3(512), 0, stream>>>(q, kk, vT, aoB);
  k_outg<<<dim3(72, 4), dim3(256), 0, stream>>>(aoB, wb + WQKV_E, out);
}